// Round 3
// baseline (369.065 us; speedup 1.0000x reference)
//
#include <hip/hip_runtime.h>
#include <math.h>

#define D_MODEL 2048
#define NE 8
#define TOKENS 16384
#define RBLK 1024          // router blocks (16 tokens each)
#define GBLK 128           // spr-gemm blocks (4 x 4 x 8 k-split)
#define KSPLIT 8

// output layout (floats): probs[16384*8], idx[16384*2], topp[16384*2], aux[1]
#define OUT_IDX   131072
#define OUT_TOPP  163840
#define OUT_AUX   196608

// ws layout (bytes)
#define WS_SPR    0        // double[1]   (zeroed)
#define WS_CNT    8        // uint[1]     (zeroed)
#define WS_GP     16       // float[8]    (zeroed)
#define WS_GC     48       // float[8]    (zeroed)
#define WS_SIMP   1024     // float[8][65536] = 2 MB, fully written by gemm blocks

// ---------------------------------------------------------------------------
// Kernel 1: fused router + SPR raw-dot GEMM.
//   blocks [0, GBLK)          : SPR gemm, 64x64 pair tile over 256-wide K slab
//   blocks [GBLK, GBLK+RBLK)  : router, 16 tokens, W in registers (2 experts/wave)
// Shared LDS budget = gemm tiles (33.3 KB) -> 4 blocks/CU; VGPR<=128 -> 4 w/SIMD.
// ---------------------------------------------------------------------------
__global__ __launch_bounds__(256, 4) void fused_main(
    const float* __restrict__ x, const float* __restrict__ W,
    const int* __restrict__ spr_idx, float* __restrict__ out,
    float* __restrict__ gP, float* __restrict__ gC, float* __restrict__ simP)
{
    __shared__ float lds[2 * 64 * 65];   // 33280 B (gemm tiles; router reuses prefix)
    const int tid = threadIdx.x;

    if (blockIdx.x >= GBLK) {
        // ================= router path =================
        const int wave = tid >> 6, lane = tid & 63;
        const int e0 = wave * 2;                       // this wave's experts: e0, e0+1
        const float4* W4 = (const float4*)W;
        float4 w0[8], w1[8];
#pragma unroll
        for (int it = 0; it < 8; ++it) {
            w0[it] = W4[(size_t)e0 * 512 + it * 64 + lane];
            w1[it] = W4[(size_t)(e0 + 1) * 512 + it * 64 + lane];
        }
        double* Ls = (double*)lds;                     // [16][8] logits
        float*  Pl = (float*)(Ls + 128);               // [8]
        float*  Cl = Pl + 8;                           // [8]
        if (tid < NE) { Pl[tid] = 0.f; Cl[tid] = 0.f; }
        __syncthreads();

        const int t0 = (int)(blockIdx.x - GBLK) * 16;
#pragma unroll 1
        for (int t = 0; t < 16; ++t) {
            const float4* xp = (const float4*)(x + (size_t)(t0 + t) * D_MODEL);
            double a0 = 0.0, a1 = 0.0;
#pragma unroll
            for (int it = 0; it < 8; ++it) {
                float4 xv = xp[it * 64 + lane];
                const double x0 = xv.x, x1 = xv.y, x2 = xv.z, x3 = xv.w;
                a0 += x0 * (double)w0[it].x + x1 * (double)w0[it].y +
                      x2 * (double)w0[it].z + x3 * (double)w0[it].w;
                a1 += x0 * (double)w1[it].x + x1 * (double)w1[it].y +
                      x2 * (double)w1[it].z + x3 * (double)w1[it].w;
            }
#pragma unroll
            for (int off = 32; off; off >>= 1) {
                a0 += __shfl_xor(a0, off, 64);
                a1 += __shfl_xor(a1, off, 64);
            }
            if (lane == 0) { Ls[t * NE + e0] = a0; Ls[t * NE + e0 + 1] = a1; }
        }
        __syncthreads();

        // epilogue: threads 0..15 each finish one token
        if (tid < 16) {
            const int tg = t0 + tid;
            double L[NE];
#pragma unroll
            for (int e = 0; e < NE; ++e) L[e] = Ls[tid * NE + e];
            int i1 = 0; double v1 = L[0];
#pragma unroll
            for (int e = 1; e < NE; ++e) if (L[e] > v1) { v1 = L[e]; i1 = e; }
            int i2 = -1; double v2 = -1e300;
#pragma unroll
            for (int e = 0; e < NE; ++e) if (e != i1 && L[e] > v2) { v2 = L[e]; i2 = e; }
            float p[NE], s = 0.f;
#pragma unroll
            for (int e = 0; e < NE; ++e) { p[e] = __expf((float)(L[e] - v1)); s += p[e]; }
            const float inv = 1.0f / s;
            float4* op = (float4*)(out + (size_t)tg * NE);
            op[0] = make_float4(p[0] * inv, p[1] * inv, p[2] * inv, p[3] * inv);
            op[1] = make_float4(p[4] * inv, p[5] * inv, p[6] * inv, p[7] * inv);
            out[OUT_IDX + tg * 2]     = (float)i1;
            out[OUT_IDX + tg * 2 + 1] = (float)i2;
            const float e2 = __expf((float)(v2 - v1));     // pr2/pr1
            out[OUT_TOPP + tg * 2]     = 1.0f / (1.0f + e2);
            out[OUT_TOPP + tg * 2 + 1] = e2 / (1.0f + e2);
#pragma unroll
            for (int e = 0; e < NE; ++e) atomicAdd(&Pl[e], p[e] * inv);
            atomicAdd(&Cl[i1], 1.f);
            atomicAdd(&Cl[i2], 1.f);
        }
        __syncthreads();
        if (tid < NE) { atomicAdd(&gP[tid], Pl[tid]); atomicAdd(&gC[tid], Cl[tid]); }
    } else {
        // ================= SPR gemm path =================
        float (*A)[65] = (float (*)[65])lds;
        float (*B)[65] = (float (*)[65])(lds + 64 * 65);
        const int b2 = blockIdx.x;
        const int bi = b2 & 3, bj = (b2 >> 2) & 3, bk = b2 >> 4;
        const int tx = tid & 15, ty = tid >> 4;
        float acc[4][4] = {};

        for (int kc = 0; kc < 4; ++kc) {
            const int k0 = bk * 256 + kc * 64;
#pragma unroll
            for (int l = 0; l < 4; ++l) {
                const int lin = l * 256 + tid;
                const int r = lin >> 4, c4 = lin & 15;
                const int ga = spr_idx[bi * 64 + r];
                float4 v = *(const float4*)(x + (size_t)ga * D_MODEL + k0 + c4 * 4);
                A[r][c4 * 4] = v.x; A[r][c4 * 4 + 1] = v.y; A[r][c4 * 4 + 2] = v.z; A[r][c4 * 4 + 3] = v.w;
                const int gb = spr_idx[bj * 64 + r];
                float4 w = *(const float4*)(x + (size_t)gb * D_MODEL + k0 + c4 * 4);
                B[r][c4 * 4] = w.x; B[r][c4 * 4 + 1] = w.y; B[r][c4 * 4 + 2] = w.z; B[r][c4 * 4 + 3] = w.w;
            }
            __syncthreads();
#pragma unroll 4
            for (int k = 0; k < 64; ++k) {
                float a[4], b[4];
#pragma unroll
                for (int u = 0; u < 4; ++u) { a[u] = A[ty * 4 + u][k]; b[u] = B[tx * 4 + u][k]; }
#pragma unroll
                for (int u = 0; u < 4; ++u)
#pragma unroll
                    for (int v = 0; v < 4; ++v) acc[u][v] += a[u] * b[v];
            }
            __syncthreads();
        }
        float* dst = simP + (size_t)bk * 65536;
#pragma unroll
        for (int u = 0; u < 4; ++u)
#pragma unroll
            for (int v = 0; v < 4; ++v) {
                const int i = bi * 64 + ty * 4 + u;
                const int j = bj * 64 + tx * 4 + v;
                dst[i * 256 + j] = acc[u][v];
            }
    }
}

// ---------------------------------------------------------------------------
// Kernel 2: SPR loss (norms from sim diagonal, router norms from `out`) +
// last-block finalize of the aux loss.
// grid 256 blocks (one per row i) x 256 threads (one per col j).
// ---------------------------------------------------------------------------
__global__ __launch_bounds__(256) void spr_finish(
    const float* __restrict__ simP, const int* __restrict__ spr_idx,
    const float* __restrict__ out_probs, const float* __restrict__ gP,
    const float* __restrict__ gC, double* __restrict__ spr_sum,
    unsigned* __restrict__ counter, float* __restrict__ out)
{
    const int i = blockIdx.x, j = threadIdx.x;
    __shared__ float rni[NE];
    __shared__ double red[4];

    // raw sims (sum K-split partials)
    float raw = 0.f, dj = 0.f;
#pragma unroll
    for (int s = 0; s < KSPLIT; ++s) raw += simP[(size_t)s * 65536 + i * 256 + j];
#pragma unroll
    for (int s = 0; s < KSPLIT; ++s) dj  += simP[(size_t)s * 65536 + j * 257];

    // router-normalized row j (and publish row i)
    const int rowj = spr_idx[j];
    const float4* pp = (const float4*)(out_probs + (size_t)rowj * NE);
    float4 pv0 = pp[0], pv1 = pp[1];
    float rs = pv0.x * pv0.x + pv0.y * pv0.y + pv0.z * pv0.z + pv0.w * pv0.w +
               pv1.x * pv1.x + pv1.y * pv1.y + pv1.z * pv1.z + pv1.w * pv1.w;
    const float rinv = 1.0f / fmaxf(sqrtf(rs), 1e-12f);
    float rnj[NE] = { pv0.x * rinv, pv0.y * rinv, pv0.z * rinv, pv0.w * rinv,
                      pv1.x * rinv, pv1.y * rinv, pv1.z * rinv, pv1.w * rinv };
    if (j == i) {
#pragma unroll
        for (int e = 0; e < NE; ++e) rni[e] = rnj[e];
        red[3] = (double)dj;                 // stash diag_i for the block
    }
    __syncthreads();
    const float di = (float)red[3];
    float rsim = 0.f;
#pragma unroll
    for (int e = 0; e < NE; ++e) rsim += rni[e] * rnj[e];
    const float ni = fmaxf(sqrtf(di), 1e-12f), nj = fmaxf(sqrtf(dj), 1e-12f);
    const float isim = raw / (ni * nj);
    const double d = (double)rsim - (double)isim;
    double sq = d * d;
#pragma unroll
    for (int off = 32; off; off >>= 1) sq += __shfl_xor(sq, off, 64);
    __syncthreads();                          // red[3] consumed; reuse red[]
    const int wave = j >> 6, lane = j & 63;
    if (lane == 0) red[wave] = sq;
    __syncthreads();
    if (j == 0) {
        atomicAdd(spr_sum, red[0] + red[1] + red[2] + red[3]);
        __threadfence();
        const unsigned old = atomicAdd(counter, 1u);
        if (old == 255u) {
            const double spr = atomicAdd(spr_sum, 0.0) / 65536.0;   // coherent read
            double lb = 0.0, dpsl = 0.0;
            for (int e = 0; e < NE; ++e) {
                const double Pi = (double)gP[e] / (double)TOKENS;
                const double fi = (double)gC[e] / (double)(TOKENS * 2);
                lb += fi * Pi;
                dpsl += 0.125 * (log(0.125) - log(Pi));
            }
            lb *= 8.0;
            out[OUT_AUX] = (float)(0.01 * (lb + dpsl + 0.1 * spr));
        }
    }
}

extern "C" void kernel_launch(void* const* d_in, const int* in_sizes, int n_in,
                              void* d_out, int out_size, void* d_ws, size_t ws_size,
                              hipStream_t stream)
{
    const float* x = (const float*)d_in[0];
    const float* W = (const float*)d_in[1];
    const int* spr_idx = (const int*)d_in[2];
    float* out = (float*)d_out;
    char* ws = (char*)d_ws;

    double*   spr_sum = (double*)(ws + WS_SPR);
    unsigned* counter = (unsigned*)(ws + WS_CNT);
    float*    gP      = (float*)(ws + WS_GP);
    float*    gC      = (float*)(ws + WS_GC);
    float*    simP    = (float*)(ws + WS_SIMP);

    hipMemsetAsync(ws, 0, 128, stream);   // spr_sum + counter + gP + gC

    fused_main<<<GBLK + RBLK, 256, 0, stream>>>(x, W, spr_idx, out, gP, gC, simP);
    spr_finish<<<256, 256, 0, stream>>>(simP, spr_idx, out, gP, gC, spr_sum, counter, out);
}

// Round 4
// 241.934 us; speedup vs baseline: 1.5255x; 1.5255x over previous
//
#include <hip/hip_runtime.h>
#include <math.h>

#define D_MODEL 2048
#define NE 8
#define TOKENS 16384

// output layout (floats): probs[16384*8], idx[16384*2], topp[16384*2], aux[1]
#define OUT_IDX   131072
#define OUT_TOPP  163840
#define OUT_AUX   196608

// ws layout (bytes)
#define WS_SPR    0        // double[1]   (zeroed)
#define WS_CNT    8        // uint[1]    (zeroed)
#define WS_GP     16       // float[8]   (zeroed)
#define WS_GC     48       // float[8]   (zeroed)
#define WS_SIMP   1024     // float[KS][65536], fully written by spr_gemm

// ---------------------------------------------------------------------------
// Router: 512 blocks x 1024 threads (16 waves), W staged in 64KB LDS,
// 2 tokens per wave. f64 logits via log-fold shuffle reduction; wave-local
// epilogue (top-2 / softmax / stores).
// ---------------------------------------------------------------------------
__global__ __launch_bounds__(1024, 8) void router_k(
    const float* __restrict__ x, const float* __restrict__ W,
    float* __restrict__ out, float* __restrict__ gP, float* __restrict__ gC)
{
    __shared__ float4 Wl[NE * 512];   // 64 KB
    __shared__ float Pl[NE], Cl[NE];
    const int tid = threadIdx.x;
    {
        const float4* W4 = (const float4*)W;
#pragma unroll
        for (int i = 0; i < 4; ++i) Wl[tid + i * 1024] = W4[tid + i * 1024];
    }
    if (tid < NE) { Pl[tid] = 0.f; Cl[tid] = 0.f; }
    __syncthreads();

    const int wave = tid >> 6, lane = tid & 63;
    const int keep5 = (lane >> 5) & 1, keep4 = (lane >> 4) & 1, keep3 = (lane >> 3) & 1;
    const int emine = keep3 + 2 * keep4 + 4 * keep5;  // expert owned after folding
    const int t0 = blockIdx.x * 32 + wave * 2;

#pragma unroll 1
    for (int tt = 0; tt < 2; ++tt) {
        const int t = t0 + tt;
        const float4* xp = (const float4*)(x + (size_t)t * D_MODEL);
        double acc[NE] = {0, 0, 0, 0, 0, 0, 0, 0};
#pragma unroll 4
        for (int it = 0; it < 8; ++it) {
            float4 xv = xp[it * 64 + lane];
            const double x0 = xv.x, x1 = xv.y, x2 = xv.z, x3 = xv.w;
#pragma unroll
            for (int e = 0; e < NE; ++e) {
                float4 wv = Wl[e * 512 + it * 64 + lane];
                acc[e] += x0 * wv.x + x1 * wv.y + x2 * wv.z + x3 * wv.w;
            }
        }
        // ---- log-fold reduce: experts fold into lane groups ----
#pragma unroll
        for (int j = 0; j < 4; ++j) {           // xor 32: keep half [4*keep5..]
            double keep = keep5 ? acc[j + 4] : acc[j];
            double send = keep5 ? acc[j] : acc[j + 4];
            acc[j] = keep + __shfl_xor(send, 32, 64);
        }
#pragma unroll
        for (int j = 0; j < 2; ++j) {           // xor 16
            double keep = keep4 ? acc[j + 2] : acc[j];
            double send = keep4 ? acc[j] : acc[j + 2];
            acc[j] = keep + __shfl_xor(send, 16, 64);
        }
        {                                        // xor 8
            double keep = keep3 ? acc[1] : acc[0];
            double send = keep3 ? acc[0] : acc[1];
            acc[0] = keep + __shfl_xor(send, 8, 64);
        }
        double L = acc[0];
        L += __shfl_xor(L, 4, 64);
        L += __shfl_xor(L, 2, 64);
        L += __shfl_xor(L, 1, 64);
        // L = logit[emine]; identical across the 8 lanes of each group.

        // top-1 across groups (lowest index wins ties)
        double v1 = L; int i1 = emine;
#pragma unroll
        for (int off = 8; off <= 32; off <<= 1) {
            double ov = __shfl_xor(v1, off, 64);
            int oi = __shfl_xor(i1, off, 64);
            if (ov > v1 || (ov == v1 && oi < i1)) { v1 = ov; i1 = oi; }
        }
        // top-2
        double v2 = (emine == i1) ? -1e300 : L;
        int i2 = (emine == i1) ? NE : emine;
#pragma unroll
        for (int off = 8; off <= 32; off <<= 1) {
            double ov = __shfl_xor(v2, off, 64);
            int oi = __shfl_xor(i2, off, 64);
            if (ov > v2 || (ov == v2 && oi < i2)) { v2 = ov; i2 = oi; }
        }
        // softmax (f32; bf16-rounded compare is loose)
        float p = __expf((float)(L - v1));
        float s = p;
#pragma unroll
        for (int off = 8; off <= 32; off <<= 1) s += __shfl_xor(s, off, 64);
        const float pr = p / s;

        if ((lane & 7) == 0) {
            out[(size_t)t * NE + emine] = pr;
            atomicAdd(&Pl[emine], pr);
        }
        if (lane == 0) {
            out[OUT_IDX + t * 2]     = (float)i1;
            out[OUT_IDX + t * 2 + 1] = (float)i2;
            const float e2 = __expf((float)(v2 - v1));   // pr2/pr1
            out[OUT_TOPP + t * 2]     = 1.0f / (1.0f + e2);
            out[OUT_TOPP + t * 2 + 1] = e2 / (1.0f + e2);
            atomicAdd(&Cl[i1], 1.f);
            atomicAdd(&Cl[i2], 1.f);
        }
    }
    __syncthreads();
    if (tid < NE) { atomicAdd(&gP[tid], Pl[tid]); atomicAdd(&gC[tid], Cl[tid]); }
}

// ---------------------------------------------------------------------------
// SPR raw-dot GEMM, grid (4,4,KS), 256 thr, 64x64 tile, 4x4 reg blocking.
// Each bk writes its own partial buffer (no atomics). nkc = 32/KS.
// ---------------------------------------------------------------------------
__global__ __launch_bounds__(256) void spr_gemm(
    const float* __restrict__ x, const int* __restrict__ spr_idx,
    float* __restrict__ simP, int nkc)
{
    __shared__ float A[64][65];
    __shared__ float B[64][65];
    __shared__ int ra[64], rb[64];
    const int bi = blockIdx.x, bj = blockIdx.y, bk = blockIdx.z;
    const int tid = threadIdx.x;
    if (tid < 64) ra[tid] = spr_idx[bi * 64 + tid];
    else if (tid < 128) rb[tid - 64] = spr_idx[bj * 64 + (tid - 64)];
    __syncthreads();

    const int tx = tid & 15, ty = tid >> 4;
    float acc[4][4] = {};

    for (int kc = 0; kc < nkc; ++kc) {
        const int k0 = (bk * nkc + kc) * 64;
#pragma unroll
        for (int l = 0; l < 4; ++l) {
            const int lin = l * 256 + tid;
            const int r = lin >> 4, c4 = lin & 15;
            float4 v = *(const float4*)(x + (size_t)ra[r] * D_MODEL + k0 + c4 * 4);
            A[r][c4 * 4] = v.x; A[r][c4 * 4 + 1] = v.y; A[r][c4 * 4 + 2] = v.z; A[r][c4 * 4 + 3] = v.w;
            float4 w = *(const float4*)(x + (size_t)rb[r] * D_MODEL + k0 + c4 * 4);
            B[r][c4 * 4] = w.x; B[r][c4 * 4 + 1] = w.y; B[r][c4 * 4 + 2] = w.z; B[r][c4 * 4 + 3] = w.w;
        }
        __syncthreads();
#pragma unroll 4
        for (int k = 0; k < 64; ++k) {
            float a[4], b[4];
#pragma unroll
            for (int u = 0; u < 4; ++u) { a[u] = A[ty * 4 + u][k]; b[u] = B[tx * 4 + u][k]; }
#pragma unroll
            for (int u = 0; u < 4; ++u)
#pragma unroll
                for (int v = 0; v < 4; ++v) acc[u][v] += a[u] * b[v];
        }
        __syncthreads();
    }
    float* dst = simP + (size_t)bk * 65536;
#pragma unroll
    for (int u = 0; u < 4; ++u)
#pragma unroll
        for (int v = 0; v < 4; ++v)
            dst[(bi * 64 + ty * 4 + u) * 256 + (bj * 64 + tx * 4 + v)] = acc[u][v];
}

// ---------------------------------------------------------------------------
// SPR loss (norms from sim diagonal, router norms from probs) + last-block
// aux-loss finalize. 256 blocks (row i) x 256 threads (col j).
// ---------------------------------------------------------------------------
__global__ __launch_bounds__(256) void spr_finish(
    const float* __restrict__ simP, const int* __restrict__ spr_idx,
    const float* __restrict__ out_probs, const float* __restrict__ gP,
    const float* __restrict__ gC, double* __restrict__ spr_sum,
    unsigned* __restrict__ counter, float* __restrict__ out, int ks)
{
    const int i = blockIdx.x, j = threadIdx.x;
    __shared__ float rni[NE];
    __shared__ double red[4];

    float raw = 0.f, dj = 0.f;
    for (int s = 0; s < ks; ++s) raw += simP[(size_t)s * 65536 + i * 256 + j];
    for (int s = 0; s < ks; ++s) dj  += simP[(size_t)s * 65536 + j * 257];

    const int rowj = spr_idx[j];
    const float4* pp = (const float4*)(out_probs + (size_t)rowj * NE);
    float4 pv0 = pp[0], pv1 = pp[1];
    float rs = pv0.x * pv0.x + pv0.y * pv0.y + pv0.z * pv0.z + pv0.w * pv0.w +
               pv1.x * pv1.x + pv1.y * pv1.y + pv1.z * pv1.z + pv1.w * pv1.w;
    const float rinv = 1.0f / fmaxf(sqrtf(rs), 1e-12f);
    float rnj[NE] = { pv0.x * rinv, pv0.y * rinv, pv0.z * rinv, pv0.w * rinv,
                      pv1.x * rinv, pv1.y * rinv, pv1.z * rinv, pv1.w * rinv };
    if (j == i) {
#pragma unroll
        for (int e = 0; e < NE; ++e) rni[e] = rnj[e];
        red[3] = (double)dj;
    }
    __syncthreads();
    const float di = (float)red[3];
    float rsim = 0.f;
#pragma unroll
    for (int e = 0; e < NE; ++e) rsim += rni[e] * rnj[e];
    const float ni = fmaxf(sqrtf(di), 1e-12f), nj = fmaxf(sqrtf(dj), 1e-12f);
    const float isim = raw / (ni * nj);
    const double d = (double)rsim - (double)isim;
    double sq = d * d;
#pragma unroll
    for (int off = 32; off; off >>= 1) sq += __shfl_xor(sq, off, 64);
    __syncthreads();
    const int wave = j >> 6, lane = j & 63;
    if (lane == 0) red[wave] = sq;
    __syncthreads();
    if (j == 0) {
        atomicAdd(spr_sum, red[0] + red[1] + red[2] + red[3]);
        __threadfence();
        const unsigned old = atomicAdd(counter, 1u);
        if (old == 255u) {
            const double spr = atomicAdd(spr_sum, 0.0) / 65536.0;
            double lb = 0.0, dpsl = 0.0;
            for (int e = 0; e < NE; ++e) {
                const double Pi = (double)gP[e] / (double)TOKENS;
                const double fi = (double)gC[e] / (double)(TOKENS * 2);
                lb += fi * Pi;
                dpsl += 0.125 * (log(0.125) - log(Pi));
            }
            lb *= 8.0;
            out[OUT_AUX] = (float)(0.01 * (lb + dpsl + 0.1 * spr));
        }
    }
}

extern "C" void kernel_launch(void* const* d_in, const int* in_sizes, int n_in,
                              void* d_out, int out_size, void* d_ws, size_t ws_size,
                              hipStream_t stream)
{
    const float* x = (const float*)d_in[0];
    const float* W = (const float*)d_in[1];
    const int* spr_idx = (const int*)d_in[2];
    float* out = (float*)d_out;
    char* ws = (char*)d_ws;

    double*   spr_sum = (double*)(ws + WS_SPR);
    unsigned* counter = (unsigned*)(ws + WS_CNT);
    float*    gP      = (float*)(ws + WS_GP);
    float*    gC      = (float*)(ws + WS_GC);
    float*    simP    = (float*)(ws + WS_SIMP);

    // pick largest K-split whose partial buffers fit the workspace
    int ks = 8;
    if (ws_size >= (size_t)WS_SIMP + 32u * 65536u * 4u) ks = 32;
    else if (ws_size >= (size_t)WS_SIMP + 16u * 65536u * 4u) ks = 16;
    const int nkc = 32 / ks;

    hipMemsetAsync(ws, 0, 128, stream);   // spr_sum + counter + gP + gC

    router_k<<<TOKENS / 32, 1024, 0, stream>>>(x, W, out, gP, gC);
    spr_gemm<<<dim3(4, 4, ks), 256, 0, stream>>>(x, spr_idx, simP, nkc);
    spr_finish<<<256, 256, 0, stream>>>(simP, spr_idx, out, gP, gC, spr_sum, counter, out, ks);
}